// Round 5
// baseline (1625.951 us; speedup 1.0000x reference)
//
#include <hip/hip_runtime.h>
#include <hip/hip_cooperative_groups.h>
#include <stdint.h>

namespace cg = cooperative_groups;

#define DD 128
#define NJ 25000
#define NI 12500
#define NSB1 ((NJ + 255) / 256)  // 98 scan blocks for off1
#define NSB2 ((NI + 255) / 256)  // 49 scan blocks for off2

__device__ __forceinline__ uint32_t rotl32(uint32_t v, int n) {
  return (v << n) | (v >> (32 - n));
}

// JAX threefry2x32, key=(0,1). Core KAT-verified vs Random123.
__device__ __forceinline__ void threefry_0_1(uint32_t& x0, uint32_t& x1) {
  const uint32_t ks0 = 0u, ks1 = 1u, ks2 = 0x1BD11BDBu;
  x0 += ks0; x1 += ks1;
#define TF_R4(a,b,c,d)                                  \
  x0 += x1; x1 = rotl32(x1,(a)); x1 ^= x0;              \
  x0 += x1; x1 = rotl32(x1,(b)); x1 ^= x0;              \
  x0 += x1; x1 = rotl32(x1,(c)); x1 ^= x0;              \
  x0 += x1; x1 = rotl32(x1,(d)); x1 ^= x0;
  TF_R4(13,15,26,6)   x0 += ks1; x1 += ks2 + 1u;
  TF_R4(17,29,16,24)  x0 += ks2; x1 += ks0 + 2u;
  TF_R4(13,15,26,6)   x0 += ks0; x1 += ks1 + 3u;
  TF_R4(17,29,16,24)  x0 += ks1; x1 += ks2 + 4u;
  TF_R4(13,15,26,6)   x0 += ks2; x1 += ks0 + 5u;
#undef TF_R4
}

// MASK IDENTIFIED (R16 sweep, unique match v5): partitionable threefry,
// ctr = (0, f), 32-bit draw = o0 ^ o1; keep <=> bit31(o0 ^ o1) == 0.
__device__ __forceinline__ bool dropout_keep(uint32_t f) {
  uint32_t x0 = 0u, x1 = f;
  threefry_0_1(x0, x1);
  return ((x0 ^ x1) >> 31) == 0u;
}

__device__ __forceinline__ float4 ld4(const float* p) {
  return *(const float4*)p;
}

// One tile of fused gather+dense. ROWS=16 (dense1) or 8 (dense2).
// Gather: 8 teams x 32 lanes, ROWS/8 rows per team, lane owns 16 B.
// Dense: thread owns ROWS/4 rows x 2 cols from LDS broadcasts.
template <int ROWS, int LAYER>
__device__ __forceinline__ void dense_tile(
    int rowBase, const float* __restrict__ xsrc, const int* __restrict__ csr,
    const int* __restrict__ offEnd, const float* __restrict__ xin,
    const float* __restrict__ WTp, const float* __restrict__ bias,
    float* __restrict__ out, int M, float* __restrict__ As, int tid) {
  __syncthreads();  // previous tile's As readers must be done
  {
    const int team = tid >> 5;
    const int l4 = (tid & 31) * 4;
    constexpr int RPT = ROWS / 8;
#pragma unroll
    for (int rr = 0; rr < RPT; ++rr) {
      const int r = team * RPT + rr;
      int rg = rowBase + r;
      if (rg >= M) rg = M - 1;  // clamped read; stores guarded below
      const int end = offEnd[rg];
      const int start = (rg == 0) ? 0 : offEnd[rg - 1];
      float4 a0 = {0.f, 0.f, 0.f, 0.f}, a1 = a0, a2 = a0, a3 = a0;
      int e = start;
      for (; e + 7 < end; e += 8) {
        int s0 = csr[e], s1 = csr[e + 1], s2 = csr[e + 2], s3 = csr[e + 3];
        int s4 = csr[e + 4], s5 = csr[e + 5], s6 = csr[e + 6], s7 = csr[e + 7];
        float4 v0 = ld4(xsrc + (size_t)s0 * DD + l4);
        float4 v1 = ld4(xsrc + (size_t)s1 * DD + l4);
        float4 v2 = ld4(xsrc + (size_t)s2 * DD + l4);
        float4 v3 = ld4(xsrc + (size_t)s3 * DD + l4);
        float4 v4 = ld4(xsrc + (size_t)s4 * DD + l4);
        float4 v5 = ld4(xsrc + (size_t)s5 * DD + l4);
        float4 v6 = ld4(xsrc + (size_t)s6 * DD + l4);
        float4 v7 = ld4(xsrc + (size_t)s7 * DD + l4);
        a0.x += v0.x; a0.y += v0.y; a0.z += v0.z; a0.w += v0.w;
        a1.x += v1.x; a1.y += v1.y; a1.z += v1.z; a1.w += v1.w;
        a2.x += v2.x; a2.y += v2.y; a2.z += v2.z; a2.w += v2.w;
        a3.x += v3.x; a3.y += v3.y; a3.z += v3.z; a3.w += v3.w;
        a0.x += v4.x; a0.y += v4.y; a0.z += v4.z; a0.w += v4.w;
        a1.x += v5.x; a1.y += v5.y; a1.z += v5.z; a1.w += v5.w;
        a2.x += v6.x; a2.y += v6.y; a2.z += v6.z; a2.w += v6.w;
        a3.x += v7.x; a3.y += v7.y; a3.z += v7.z; a3.w += v7.w;
      }
      for (; e + 3 < end; e += 4) {
        int s0 = csr[e], s1 = csr[e + 1], s2 = csr[e + 2], s3 = csr[e + 3];
        float4 v0 = ld4(xsrc + (size_t)s0 * DD + l4);
        float4 v1 = ld4(xsrc + (size_t)s1 * DD + l4);
        float4 v2 = ld4(xsrc + (size_t)s2 * DD + l4);
        float4 v3 = ld4(xsrc + (size_t)s3 * DD + l4);
        a0.x += v0.x; a0.y += v0.y; a0.z += v0.z; a0.w += v0.w;
        a1.x += v1.x; a1.y += v1.y; a1.z += v1.z; a1.w += v1.w;
        a2.x += v2.x; a2.y += v2.y; a2.z += v2.z; a2.w += v2.w;
        a3.x += v3.x; a3.y += v3.y; a3.z += v3.z; a3.w += v3.w;
      }
      for (; e < end; ++e) {
        float4 v = ld4(xsrc + (size_t)csr[e] * DD + l4);
        a0.x += v.x; a0.y += v.y; a0.z += v.z; a0.w += v.w;
      }
      a0.x += a1.x + a2.x + a3.x;
      a0.y += a1.y + a2.y + a3.y;
      a0.z += a1.z + a2.z + a3.z;
      a0.w += a1.w + a2.w + a3.w;
      float rdeg = 1.0f / fmaxf((float)(end - start), 1.0f);
      a0.x *= rdeg; a0.y *= rdeg; a0.z *= rdeg; a0.w *= rdeg;
      *(float4*)(As + r * 256 + l4) = a0;
      *(float4*)(As + r * 256 + DD + l4) = ld4(xin + (size_t)rg * DD + l4);
    }
  }
  __syncthreads();

  const int u = tid & 63;  // cols u, u+64
  const int g = tid >> 6;  // wave-uniform row group
  constexpr int RPR = ROWS / 4;
  const int r0 = g * RPR;
  float acc[RPR][2];
#pragma unroll
  for (int r = 0; r < RPR; ++r) acc[r][0] = acc[r][1] = 0.f;

#pragma unroll 8
  for (int k0 = 0; k0 < 256; k0 += 4) {
    const float* wbase = WTp + (k0 >> 2) * (DD * 4);
    float4 w0 = ld4(wbase + u * 4);
    float4 w1 = ld4(wbase + (u + 64) * 4);
#pragma unroll
    for (int r = 0; r < RPR; ++r) {
      float4 a = *(const float4*)(As + (r0 + r) * 256 + k0);
      acc[r][0] += a.x * w0.x + a.y * w0.y + a.z * w0.z + a.w * w0.w;
      acc[r][1] += a.x * w1.x + a.y * w1.y + a.z * w1.z + a.w * w1.w;
    }
  }

  const float bb0 = bias[u];
  const float bb1 = bias[u + 64];
#pragma unroll
  for (int r = 0; r < RPR; ++r) {
    int rg = rowBase + r0 + r;
    if (rg >= M) continue;
    float v0 = acc[r][0] + bb0;
    float v1 = acc[r][1] + bb1;
    if (LAYER == 1) {
      v0 = fmaxf(v0, 0.0f);
      v1 = fmaxf(v1, 0.0f);
      uint32_t fb = (uint32_t)rg * DD;
      v0 = dropout_keep(fb + (uint32_t)u) ? v0 * 2.0f : 0.0f;
      v1 = dropout_keep(fb + (uint32_t)u + 64u) ? v1 * 2.0f : 0.0f;
    }
    out[(size_t)rg * DD + u] = v0;
    out[(size_t)rg * DD + u + 64] = v1;
  }
}

// One cooperative kernel: setup -> hist -> scan(3 steps) -> fill ->
// dense1 -> dense2, with grid.sync() + device-scope fences (per-XCD L2s
// are not cross-coherent; __threadfence is the agent-scope release/acquire).
__global__ __launch_bounds__(256, 6) void mega_kernel(
    const float* __restrict__ feat, const int* __restrict__ adj1,
    const int* __restrict__ adj2, const float* __restrict__ Wl1,
    const float* __restrict__ Wr1, const float* __restrict__ bias1,
    const float* __restrict__ Wl2, const float* __restrict__ Wr2,
    const float* __restrict__ bias2, float* __restrict__ x1,
    float* __restrict__ WT1, float* __restrict__ WT2, int* __restrict__ off1,
    int* __restrict__ off2, int* __restrict__ blockSums,
    int* __restrict__ flag, int* __restrict__ csr1, int* __restrict__ csr2,
    float* __restrict__ outp, int E1, int E2) {
  cg::grid_group grid = cg::this_grid();
  __shared__ __align__(16) char smem[16 * 256 * 4];  // 16 KB
  float* As = (float*)smem;
  int* iAs = (int*)smem;
  const int tid = threadIdx.x;
  const int b = blockIdx.x;
  const int gtid = b * 256 + tid;
  const int nthr = gridDim.x * 256;

  // ---- phase 0: weight prep + zero hists + i64 detect ----
  for (int t = gtid; t < 2 * DD * 256; t += nthr) {
    int which = t >= DD * 256;
    int idx = which ? t - DD * 256 : t;
    const float* Wl = which ? Wl2 : Wl1;
    const float* Wr = which ? Wr2 : Wr1;
    float* WTp = which ? WT2 : WT1;
    int c = idx >> 8;
    int k = idx & 255;
    float v = (k < DD) ? Wl[c * DD + k] : Wr[c * DD + (k - DD)];
    WTp[(k >> 2) * (DD * 4) + c * 4 + (k & 3)] = v;
  }
  for (int i = gtid; i < NJ + NI; i += nthr) {
    if (i < NJ) off1[i] = 0; else off2[i - NJ] = 0;
  }
  if (gtid == 0) {
    int is64 = 1;
    for (int e = 0; e < 16; ++e)
      if (adj1[2 * e + 1] != 0) is64 = 0;
    *flag = is64;
  }
  __threadfence();
  grid.sync();
  __threadfence();

  const int f = *flag;

  // ---- phase 1: histogram (degree counts) ----
  for (int t = gtid; t < E1 + E2; t += nthr) {
    if (t < E1) {
      int d = f ? adj1[2 * E1 + 2 * t] : adj1[E1 + t];
      if (d < NJ) atomicAdd(&off1[d], 1);
    } else {
      int e = t - E1;
      int d = f ? adj2[2 * E2 + 2 * e] : adj2[E2 + e];
      if (d < NI) atomicAdd(&off2[d], 1);
    }
  }
  __threadfence();
  grid.sync();
  __threadfence();

  // ---- phase 2: scan step A — per-block exclusive scan + block totals ----
  if (b < NSB1 + NSB2) {
    int* arr = (b < NSB1) ? off1 : off2;
    const int len = (b < NSB1) ? NJ : NI;
    const int i = ((b < NSB1) ? b : (b - NSB1)) * 256 + tid;
    int v = (i < len) ? arr[i] : 0;
    iAs[tid] = v;
    __syncthreads();
    int x = v;
    for (int ofs = 1; ofs < 256; ofs <<= 1) {
      int y = (tid >= ofs) ? iAs[tid - ofs] : 0;
      __syncthreads();
      x += y;
      iAs[tid] = x;
      __syncthreads();
    }
    if (i < len) arr[i] = x - v;        // exclusive within block
    if (tid == 255) blockSums[b] = x;   // block total
  }
  __threadfence();
  grid.sync();
  __threadfence();

  // ---- phase 3: scan step B — scan block totals (per segment) ----
  if (b < 2) {
    const int base = b ? NSB1 : 0;
    const int cnt = b ? NSB2 : NSB1;
    int v = (tid < cnt) ? blockSums[base + tid] : 0;
    iAs[tid] = v;
    __syncthreads();
    int x = v;
    for (int ofs = 1; ofs < 256; ofs <<= 1) {
      int y = (tid >= ofs) ? iAs[tid - ofs] : 0;
      __syncthreads();
      x += y;
      iAs[tid] = x;
      __syncthreads();
    }
    if (tid < cnt) blockSums[base + tid] = x - v;  // exclusive
  }
  __threadfence();
  grid.sync();
  __threadfence();

  // ---- phase 4: scan step C — add scanned block offsets ----
  if (b < NSB1 + NSB2) {
    int* arr = (b < NSB1) ? off1 : off2;
    const int len = (b < NSB1) ? NJ : NI;
    const int i = ((b < NSB1) ? b : (b - NSB1)) * 256 + tid;
    if (i < len) arr[i] += blockSums[b];
  }
  __threadfence();
  grid.sync();
  __threadfence();

  // ---- phase 5: fill CSR. off*: exclusive starts -> inclusive ENDS ----
  for (int t = gtid; t < E1 + E2; t += nthr) {
    if (t < E1) {
      int s, d;
      if (f) {
        int2 ps = *(const int2*)(adj1 + 2 * t);
        int2 pd = *(const int2*)(adj1 + 2 * E1 + 2 * t);
        s = ps.x; d = pd.x;
      } else {
        s = adj1[t];
        d = adj1[E1 + t];
      }
      if (d < NJ) csr1[atomicAdd(&off1[d], 1)] = s;
    } else {
      int e = t - E1;
      int s, d;
      if (f) {
        int2 ps = *(const int2*)(adj2 + 2 * e);
        int2 pd = *(const int2*)(adj2 + 2 * E2 + 2 * e);
        s = ps.x; d = pd.x;
      } else {
        s = adj2[e];
        d = adj2[E2 + e];
      }
      if (d < NI) csr2[atomicAdd(&off2[d], 1)] = s;
    }
  }
  __threadfence();
  grid.sync();
  __threadfence();

  // ---- phase 6: layer-1 fused gather+dense (16-row tiles) ----
  const int nT1 = (NJ + 15) / 16;
  for (int t = b; t < nT1; t += gridDim.x)
    dense_tile<16, 1>(t * 16, feat, csr1, off1, feat, WT1, bias1, x1, NJ, As,
                      tid);
  __threadfence();
  grid.sync();
  __threadfence();

  // ---- phase 7: layer-2 fused gather+dense (8-row tiles) ----
  const int nT2 = (NI + 7) / 8;
  for (int t = b; t < nT2; t += gridDim.x)
    dense_tile<8, 2>(t * 8, x1, csr2, off2, x1, WT2, bias2, outp, NI, As, tid);
}

extern "C" void kernel_launch(void* const* d_in, const int* in_sizes, int n_in,
                              void* d_out, int out_size, void* d_ws,
                              size_t ws_size, hipStream_t stream) {
  const float* feat = (const float*)d_in[0];  // fp32 (R4 NaN proof)
  const int* t_adj = (const int*)d_in[1];
  const int* n_adj = (const int*)d_in[2];
  const float* W1l = (const float*)d_in[5];
  const float* b1 = (const float*)d_in[6];
  const float* W1r = (const float*)d_in[7];
  const float* W2l = (const float*)d_in[8];
  const float* b2 = (const float*)d_in[9];
  const float* W2r = (const float*)d_in[10];

  const int E1 = in_sizes[1] / 2;
  const int E2 = in_sizes[2] / 2;

  // Workspace ~17 MB.
  float* ws = (float*)d_ws;
  float* x1 = ws;                        // 3,200,000 f
  float* WT1 = x1 + 3200000;             //    32,768 f
  float* WT2 = WT1 + 32768;              //    32,768 f
  int* off1 = (int*)(WT2 + 32768);       //    NJ
  int* off2 = off1 + NJ;                 //    NI (contiguous after off1)
  int* blockSums = off2 + NI;            //    256
  int* flagIdx = blockSums + 256;        //    1 (+pad to 16)
  int* csr1 = flagIdx + 16;              //    E1 (max)
  int* csr2 = csr1 + E1;                 //    E2 (max)

  static int gridBlocks = 0;
  if (gridBlocks == 0) {
    hipDeviceProp_t prop;
    hipGetDeviceProperties(&prop, 0);
    int maxB = 0;
    hipOccupancyMaxActiveBlocksPerMultiprocessor(
        &maxB, (const void*)mega_kernel, 256, 0);
    if (maxB < 1) maxB = 1;
    long g = (long)maxB * prop.multiProcessorCount;
    if (g > 1563) g = 1563;  // = tile count of both dense phases
    gridBlocks = (int)g;
  }

  float* outp = (float*)d_out;
  void* args[] = {&feat, &t_adj, &n_adj, &W1l,  &W1r,       &b1,
                  &W2l,  &W2r,   &b2,    &x1,   &WT1,       &WT2,
                  &off1, &off2,  &blockSums,    &flagIdx,   &csr1,
                  &csr2, &outp,  (void*)&E1,    (void*)&E2};
  hipLaunchCooperativeKernel((const void*)mega_kernel, dim3(gridBlocks),
                             dim3(256), (void**)args, 0, stream);
}

// Round 6
// 284.632 us; speedup vs baseline: 5.7125x; 5.7125x over previous
//
#include <hip/hip_runtime.h>
#include <stdint.h>

#define DD 128
#define NJ 25000
#define NI 12500

__device__ __forceinline__ uint32_t rotl32(uint32_t v, int n) {
  return (v << n) | (v >> (32 - n));
}

// JAX threefry2x32, key=(0,1). Core KAT-verified vs Random123.
__device__ __forceinline__ void threefry_0_1(uint32_t& x0, uint32_t& x1) {
  const uint32_t ks0 = 0u, ks1 = 1u, ks2 = 0x1BD11BDBu;
  x0 += ks0; x1 += ks1;
#define TF_R4(a,b,c,d)                                  \
  x0 += x1; x1 = rotl32(x1,(a)); x1 ^= x0;              \
  x0 += x1; x1 = rotl32(x1,(b)); x1 ^= x0;              \
  x0 += x1; x1 = rotl32(x1,(c)); x1 ^= x0;              \
  x0 += x1; x1 = rotl32(x1,(d)); x1 ^= x0;
  TF_R4(13,15,26,6)   x0 += ks1; x1 += ks2 + 1u;
  TF_R4(17,29,16,24)  x0 += ks2; x1 += ks0 + 2u;
  TF_R4(13,15,26,6)   x0 += ks0; x1 += ks1 + 3u;
  TF_R4(17,29,16,24)  x0 += ks1; x1 += ks2 + 4u;
  TF_R4(13,15,26,6)   x0 += ks2; x1 += ks0 + 5u;
#undef TF_R4
}

// MASK IDENTIFIED (R16 sweep, unique match v5): partitionable threefry,
// ctr = (0, f), 32-bit draw = o0 ^ o1; keep <=> bit31(o0 ^ o1) == 0.
__device__ __forceinline__ bool dropout_keep(uint32_t f) {
  uint32_t x0 = 0u, x1 = f;
  threefry_0_1(x0, x1);
  return ((x0 ^ x1) >> 31) == 0u;
}

__device__ __forceinline__ float4 ld4(const float* p) {
  return *(const float4*)p;
}

// Per-block inline int64-as-int32-pairs detect (odd words zero; L2-hit).
__device__ __forceinline__ int detect_flag_block(const int* __restrict__ w,
                                                 int* sf) {
  if (threadIdx.x == 0) {
    int is64 = 1;
    for (int e = 0; e < 16; ++e)
      if (w[2 * e + 1] != 0) is64 = 0;
    *sf = is64;
  }
  __syncthreads();
  return *sf;
}

// Fused setup+hist (one dispatch; off arrays pre-zeroed by memsetAsync):
//   blocks 0..255 : weight prep for BOTH layers
//   blocks 256..  : degree histogram over both edge lists
// WTp[(k>>2)*512 + c*4 + (k&3)] = Wcat[c][k]; Wcat = [W_l | W_r] along k.
__global__ void setup_hist(const float* __restrict__ Wl1,
                           const float* __restrict__ Wr1,
                           float* __restrict__ WT1,
                           const float* __restrict__ Wl2,
                           const float* __restrict__ Wr2,
                           float* __restrict__ WT2,
                           const int* __restrict__ adj1,
                           const int* __restrict__ adj2,
                           int* __restrict__ cnt1, int* __restrict__ cnt2,
                           int nE1, int nE2) {
  const int b = blockIdx.x;
  if (b < 256) {
    int t = b * 256 + threadIdx.x;  // exactly covers 2*DD*256 = 65536
    int which = t >= DD * 256;
    int idx = which ? t - DD * 256 : t;
    const float* Wl = which ? Wl2 : Wl1;
    const float* Wr = which ? Wr2 : Wr1;
    float* WTp = which ? WT2 : WT1;
    int c = idx >> 8;
    int k = idx & 255;
    float v = (k < DD) ? Wl[c * DD + k] : Wr[c * DD + (k - DD)];
    WTp[(k >> 2) * (DD * 4) + c * 4 + (k & 3)] = v;
    return;
  }
  __shared__ int sf;
  const int f = detect_flag_block(adj1, &sf);
  int t = (b - 256) * 256 + threadIdx.x;
  if (t < nE1) {
    int d = f ? adj1[2 * nE1 + 2 * t] : adj1[nE1 + t];
    if (d < NJ) atomicAdd(&cnt1[d], 1);
  } else if (t < nE1 + nE2) {
    int e = t - nE1;
    int d = f ? adj2[2 * nE2 + 2 * e] : adj2[nE2 + e];
    if (d < NI) atomicAdd(&cnt2[d], 1);
  }
}

// In-place exclusive scan; block 0 -> (a1,n1), block 1 -> (a2,n2).
__global__ void scan2(int* __restrict__ a1, int n1, int* __restrict__ a2,
                      int n2) {
  __shared__ int part[1024];
  int* a = blockIdx.x ? a2 : a1;
  const int n = blockIdx.x ? n2 : n1;
  const int t = threadIdx.x;
  const int per = (n + 1023) / 1024;
  int lo = t * per;
  int hi = lo + per;
  if (hi > n) hi = n;
  int sum = 0;
  for (int i = lo; i < hi; ++i) sum += a[i];
  part[t] = sum;
  __syncthreads();
  for (int ofs = 1; ofs < 1024; ofs <<= 1) {
    int v = (t >= ofs) ? part[t - ofs] : 0;
    __syncthreads();
    part[t] += v;
    __syncthreads();
  }
  int run = (t == 0) ? 0 : part[t - 1];
  for (int i = lo; i < hi; ++i) {
    int v = a[i];
    a[i] = run;
    run += v;
  }
}

// fill: cur[] holds exclusive starts on entry; inclusive ENDS on exit
// (cur[d] == off[d+1]); gather derives start = (d ? cur[d-1] : 0).
__global__ void fill_both(const int* __restrict__ adj1,
                          const int* __restrict__ adj2,
                          int* __restrict__ cur1, int* __restrict__ cur2,
                          int* __restrict__ csr1, int* __restrict__ csr2,
                          int nE1, int nE2) {
  __shared__ int sf;
  const int f = detect_flag_block(adj1, &sf);
  int t = blockIdx.x * blockDim.x + threadIdx.x;
  if (t < nE1) {
    int s, d;
    if (f) {
      s = adj1[2 * t];
      d = adj1[2 * nE1 + 2 * t];
    } else {
      s = adj1[t];
      d = adj1[nE1 + t];
    }
    if (d < NJ) csr1[atomicAdd(&cur1[d], 1)] = s;
  } else if (t < nE1 + nE2) {
    int e = t - nE1;
    int s, d;
    if (f) {
      s = adj2[2 * e];
      d = adj2[2 * nE2 + 2 * e];
    } else {
      s = adj2[e];
      d = adj2[nE2 + e];
    }
    if (d < NI) csr2[atomicAdd(&cur2[d], 1)] = s;
  }
}

// Fused gather + dense, ROWS rows/block (32 for layer1, 16 for layer2 —
// empirically fastest split from R3/R4).
// Gather: 8 teams x 32 lanes, ROWS/8 rows per team, lane owns 16 B.
// Dense: thread owns ROWS/8 rows x 4 cols (u, u+32, u+64, u+96) — halves
// LDS broadcast reads per FMA vs the 2-col shape (LDS-issue relief); each
// W load is lane-contiguous (u*16 B) = perfectly coalesced.
// LAYER==1: relu + dropout epilogue.
template <int ROWS, int LAYER>
__global__ __launch_bounds__(256) void dense_kernel(
    const float* __restrict__ xsrc, const int* __restrict__ csr,
    const int* __restrict__ offEnd, const float* __restrict__ xin,
    const float* __restrict__ WTp, const float* __restrict__ bias,
    float* __restrict__ out, int M) {
  __shared__ float As[ROWS * 256];
  const int tid = threadIdx.x;
  const int rowBase = blockIdx.x * ROWS;
  constexpr int RPT = ROWS / 8;  // rows per gather-team == rows per thread

  // ---- gather phase ----
  {
    const int team = tid >> 5;      // 0..7
    const int l4 = (tid & 31) * 4;  // float4 slot within row
#pragma unroll
    for (int rr = 0; rr < RPT; ++rr) {
      const int r = team * RPT + rr;
      int rg = rowBase + r;
      if (rg >= M) rg = M - 1;  // clamped read; stores guarded below
      const int end = offEnd[rg];
      const int start = (rg == 0) ? 0 : offEnd[rg - 1];
      float4 a0 = {0.f, 0.f, 0.f, 0.f}, a1 = a0, a2 = a0, a3 = a0;
      int e = start;
      for (; e + 7 < end; e += 8) {
        int s0 = csr[e], s1 = csr[e + 1], s2 = csr[e + 2], s3 = csr[e + 3];
        int s4 = csr[e + 4], s5 = csr[e + 5], s6 = csr[e + 6], s7 = csr[e + 7];
        float4 v0 = ld4(xsrc + (size_t)s0 * DD + l4);
        float4 v1 = ld4(xsrc + (size_t)s1 * DD + l4);
        float4 v2 = ld4(xsrc + (size_t)s2 * DD + l4);
        float4 v3 = ld4(xsrc + (size_t)s3 * DD + l4);
        float4 v4 = ld4(xsrc + (size_t)s4 * DD + l4);
        float4 v5 = ld4(xsrc + (size_t)s5 * DD + l4);
        float4 v6 = ld4(xsrc + (size_t)s6 * DD + l4);
        float4 v7 = ld4(xsrc + (size_t)s7 * DD + l4);
        a0.x += v0.x; a0.y += v0.y; a0.z += v0.z; a0.w += v0.w;
        a1.x += v1.x; a1.y += v1.y; a1.z += v1.z; a1.w += v1.w;
        a2.x += v2.x; a2.y += v2.y; a2.z += v2.z; a2.w += v2.w;
        a3.x += v3.x; a3.y += v3.y; a3.z += v3.z; a3.w += v3.w;
        a0.x += v4.x; a0.y += v4.y; a0.z += v4.z; a0.w += v4.w;
        a1.x += v5.x; a1.y += v5.y; a1.z += v5.z; a1.w += v5.w;
        a2.x += v6.x; a2.y += v6.y; a2.z += v6.z; a2.w += v6.w;
        a3.x += v7.x; a3.y += v7.y; a3.z += v7.z; a3.w += v7.w;
      }
      for (; e + 3 < end; e += 4) {
        int s0 = csr[e], s1 = csr[e + 1], s2 = csr[e + 2], s3 = csr[e + 3];
        float4 v0 = ld4(xsrc + (size_t)s0 * DD + l4);
        float4 v1 = ld4(xsrc + (size_t)s1 * DD + l4);
        float4 v2 = ld4(xsrc + (size_t)s2 * DD + l4);
        float4 v3 = ld4(xsrc + (size_t)s3 * DD + l4);
        a0.x += v0.x; a0.y += v0.y; a0.z += v0.z; a0.w += v0.w;
        a1.x += v1.x; a1.y += v1.y; a1.z += v1.z; a1.w += v1.w;
        a2.x += v2.x; a2.y += v2.y; a2.z += v2.z; a2.w += v2.w;
        a3.x += v3.x; a3.y += v3.y; a3.z += v3.z; a3.w += v3.w;
      }
      for (; e < end; ++e) {
        float4 v = ld4(xsrc + (size_t)csr[e] * DD + l4);
        a0.x += v.x; a0.y += v.y; a0.z += v.z; a0.w += v.w;
      }
      a0.x += a1.x + a2.x + a3.x;
      a0.y += a1.y + a2.y + a3.y;
      a0.z += a1.z + a2.z + a3.z;
      a0.w += a1.w + a2.w + a3.w;
      float rdeg = 1.0f / fmaxf((float)(end - start), 1.0f);
      a0.x *= rdeg; a0.y *= rdeg; a0.z *= rdeg; a0.w *= rdeg;
      *(float4*)(As + r * 256 + l4) = a0;
      *(float4*)(As + r * 256 + DD + l4) = ld4(xin + (size_t)rg * DD + l4);
    }
  }
  __syncthreads();

  // ---- dense phase: RPT rows x 4 cols per thread ----
  const int u = tid & 31;   // cols u, u+32, u+64, u+96
  const int g = tid >> 5;   // row group 0..7 (wave-uniform)
  const int r0 = g * RPT;
  float acc[RPT][4];
#pragma unroll
  for (int r = 0; r < RPT; ++r)
    acc[r][0] = acc[r][1] = acc[r][2] = acc[r][3] = 0.f;

#pragma unroll 8
  for (int k0 = 0; k0 < 256; k0 += 4) {
    const float* wbase = WTp + (k0 >> 2) * (DD * 4);
    float4 w0 = ld4(wbase + u * 4);
    float4 w1 = ld4(wbase + (u + 32) * 4);
    float4 w2 = ld4(wbase + (u + 64) * 4);
    float4 w3 = ld4(wbase + (u + 96) * 4);
#pragma unroll
    for (int r = 0; r < RPT; ++r) {
      float4 a = *(const float4*)(As + (r0 + r) * 256 + k0);
      acc[r][0] += a.x * w0.x + a.y * w0.y + a.z * w0.z + a.w * w0.w;
      acc[r][1] += a.x * w1.x + a.y * w1.y + a.z * w1.z + a.w * w1.w;
      acc[r][2] += a.x * w2.x + a.y * w2.y + a.z * w2.z + a.w * w2.w;
      acc[r][3] += a.x * w3.x + a.y * w3.y + a.z * w3.z + a.w * w3.w;
    }
  }

  float bb[4] = {bias[u], bias[u + 32], bias[u + 64], bias[u + 96]};
#pragma unroll
  for (int r = 0; r < RPT; ++r) {
    int rg = rowBase + r0 + r;
    if (rg >= M) continue;
#pragma unroll
    for (int i = 0; i < 4; ++i) {
      int cc = u + 32 * i;
      float v = acc[r][i] + bb[i];
      if (LAYER == 1) {
        v = fmaxf(v, 0.0f);
        v = dropout_keep((uint32_t)rg * DD + (uint32_t)cc) ? v * 2.0f : 0.0f;
      }
      out[(size_t)rg * DD + cc] = v;
    }
  }
}

extern "C" void kernel_launch(void* const* d_in, const int* in_sizes, int n_in,
                              void* d_out, int out_size, void* d_ws, size_t ws_size,
                              hipStream_t stream) {
  const float* feat = (const float*)d_in[0];   // fp32 (R4 NaN proof)
  const int* t_adj = (const int*)d_in[1];
  const int* n_adj = (const int*)d_in[2];
  const float* W1l = (const float*)d_in[5];
  const float* b1 = (const float*)d_in[6];
  const float* W1r = (const float*)d_in[7];
  const float* W2l = (const float*)d_in[8];
  const float* b2 = (const float*)d_in[9];
  const float* W2r = (const float*)d_in[10];

  const int E1 = in_sizes[1] / 2;
  const int E2 = in_sizes[2] / 2;

  // Workspace ~16 MB.
  float* ws = (float*)d_ws;
  float* x1 = ws;                       // 3,200,000 f
  float* WT1 = x1 + 3200000;            //    32,768 f
  float* WT2 = WT1 + 32768;             //    32,768 f
  int* off1 = (int*)(WT2 + 32768);      //    NJ
  int* off2 = off1 + NJ;                //    NI (contiguous after off1)
  int* csr1 = off2 + NI;                //    E1 (max)
  int* csr2 = csr1 + E1;                //    E2 (max)

  hipMemsetAsync(off1, 0, (size_t)(NJ + NI) * sizeof(int), stream);

  const int nTot = E1 + E2;
  const int histBlocks = (nTot + 255) / 256;
  setup_hist<<<256 + histBlocks, 256, 0, stream>>>(
      W1l, W1r, WT1, W2l, W2r, WT2, t_adj, n_adj, off1, off2, E1, E2);

  scan2<<<2, 1024, 0, stream>>>(off1, NJ, off2, NI);

  fill_both<<<(nTot + 255) / 256, 256, 0, stream>>>(t_adj, n_adj, off1, off2,
                                                    csr1, csr2, E1, E2);

  dense_kernel<32, 1><<<(NJ + 31) / 32, 256, 0, stream>>>(
      feat, csr1, off1, feat, WT1, b1, x1, NJ);
  dense_kernel<16, 2><<<(NI + 15) / 16, 256, 0, stream>>>(
      x1, csr2, off2, x1, WT2, b2, (float*)d_out, NI);
}

// Round 7
// 228.610 us; speedup vs baseline: 7.1123x; 1.2451x over previous
//
#include <hip/hip_runtime.h>
#include <stdint.h>

#define DD 128
#define NJ 25000
#define NI 12500
#define OVCAP 65536  // overflow-list capacity per layer (pairs)

__device__ __forceinline__ uint32_t rotl32(uint32_t v, int n) {
  return (v << n) | (v >> (32 - n));
}

// JAX threefry2x32, key=(0,1). Core KAT-verified vs Random123.
__device__ __forceinline__ void threefry_0_1(uint32_t& x0, uint32_t& x1) {
  const uint32_t ks0 = 0u, ks1 = 1u, ks2 = 0x1BD11BDBu;
  x0 += ks0; x1 += ks1;
#define TF_R4(a,b,c,d)                                  \
  x0 += x1; x1 = rotl32(x1,(a)); x1 ^= x0;              \
  x0 += x1; x1 = rotl32(x1,(b)); x1 ^= x0;              \
  x0 += x1; x1 = rotl32(x1,(c)); x1 ^= x0;              \
  x0 += x1; x1 = rotl32(x1,(d)); x1 ^= x0;
  TF_R4(13,15,26,6)   x0 += ks1; x1 += ks2 + 1u;
  TF_R4(17,29,16,24)  x0 += ks2; x1 += ks0 + 2u;
  TF_R4(13,15,26,6)   x0 += ks0; x1 += ks1 + 3u;
  TF_R4(17,29,16,24)  x0 += ks1; x1 += ks2 + 4u;
  TF_R4(13,15,26,6)   x0 += ks2; x1 += ks0 + 5u;
#undef TF_R4
}

// MASK IDENTIFIED (R16 sweep, unique match v5): partitionable threefry,
// ctr = (0, f), 32-bit draw = o0 ^ o1; keep <=> bit31(o0 ^ o1) == 0.
__device__ __forceinline__ bool dropout_keep(uint32_t f) {
  uint32_t x0 = 0u, x1 = f;
  threefry_0_1(x0, x1);
  return ((x0 ^ x1) >> 31) == 0u;
}

__device__ __forceinline__ float4 ld4(const float* p) {
  return *(const float4*)p;
}

// Per-block inline int64-as-int32-pairs detect (odd words zero; L2-hit).
__device__ __forceinline__ int detect_flag_block(const int* __restrict__ w,
                                                 int* sf) {
  if (threadIdx.x == 0) {
    int is64 = 1;
    for (int e = 0; e < 16; ++e)
      if (w[2 * e + 1] != 0) is64 = 0;
    *sf = is64;
  }
  __syncthreads();
  return *sf;
}

// One-pass padded-bucket CSR build fused with weight prep.
//   blocks 0..255 : weight prep for BOTH layers
//   blocks 256..  : edge pass — pos=atomicAdd(cnt[d]); bucket or overflow
// cnt arrays pre-zeroed by memsetAsync. Overflow (deg>CAP) edges go to a
// compact (d,s) list; gather handles them exactly (rare: Poisson(~24) tail).
// WTp[(k>>2)*512 + c*4 + (k&3)] = Wcat[c][k]; Wcat = [W_l | W_r] along k.
__global__ void setup_bucket(const float* __restrict__ Wl1,
                             const float* __restrict__ Wr1,
                             float* __restrict__ WT1,
                             const float* __restrict__ Wl2,
                             const float* __restrict__ Wr2,
                             float* __restrict__ WT2,
                             const int* __restrict__ adj1,
                             const int* __restrict__ adj2,
                             int* __restrict__ cnt1, int* __restrict__ cnt2,
                             int* __restrict__ ovCnt,
                             int* __restrict__ ovList1,
                             int* __restrict__ ovList2,
                             int* __restrict__ bucket1,
                             int* __restrict__ bucket2,
                             int nE1, int nE2, int CAP) {
  const int b = blockIdx.x;
  if (b < 256) {
    int t = b * 256 + threadIdx.x;  // exactly covers 2*DD*256 = 65536
    int which = t >= DD * 256;
    int idx = which ? t - DD * 256 : t;
    const float* Wl = which ? Wl2 : Wl1;
    const float* Wr = which ? Wr2 : Wr1;
    float* WTp = which ? WT2 : WT1;
    int c = idx >> 8;
    int k = idx & 255;
    float v = (k < DD) ? Wl[c * DD + k] : Wr[c * DD + (k - DD)];
    WTp[(k >> 2) * (DD * 4) + c * 4 + (k & 3)] = v;
    return;
  }
  __shared__ int sf;
  const int f = detect_flag_block(adj1, &sf);
  int t = (b - 256) * 256 + threadIdx.x;
  if (t < nE1) {
    int s, d;
    if (f) {
      s = adj1[2 * t];
      d = adj1[2 * nE1 + 2 * t];
    } else {
      s = adj1[t];
      d = adj1[nE1 + t];
    }
    if (d < NJ) {
      int pos = atomicAdd(&cnt1[d], 1);
      if (pos < CAP) {
        bucket1[(size_t)d * CAP + pos] = s;
      } else {
        int op = atomicAdd(&ovCnt[0], 1);
        if (op < OVCAP) { ovList1[2 * op] = d; ovList1[2 * op + 1] = s; }
      }
    }
  } else if (t < nE1 + nE2) {
    int e = t - nE1;
    int s, d;
    if (f) {
      s = adj2[2 * e];
      d = adj2[2 * nE2 + 2 * e];
    } else {
      s = adj2[e];
      d = adj2[nE2 + e];
    }
    if (d < NI) {
      int pos = atomicAdd(&cnt2[d], 1);
      if (pos < CAP) {
        bucket2[(size_t)d * CAP + pos] = s;
      } else {
        int op = atomicAdd(&ovCnt[1], 1);
        if (op < OVCAP) { ovList2[2 * op] = d; ovList2[2 * op + 1] = s; }
      }
    }
  }
}

// Fused gather + dense, ROWS rows/block (32 for layer1, 16 for layer2).
// Gather: 8 teams x 32 lanes, ROWS/8 rows per team, lane owns 16 B; reads
// the row's padded bucket (min(deg,CAP) entries) + rare overflow-list scan.
// Dense: thread owns ROWS/8 rows x 4 cols; As reads are wave-uniform.
// LAYER==1: relu + dropout epilogue.
template <int ROWS, int LAYER>
__global__ __launch_bounds__(256) void dense_kernel(
    const float* __restrict__ xsrc, const int* __restrict__ bucket,
    const int* __restrict__ cnt, const int* __restrict__ ovCnt,
    const int* __restrict__ ovList, const float* __restrict__ xin,
    const float* __restrict__ WTp, const float* __restrict__ bias,
    float* __restrict__ out, int M, int CAP) {
  __shared__ float As[ROWS * 256];
  const int tid = threadIdx.x;
  const int rowBase = blockIdx.x * ROWS;
  constexpr int RPT = ROWS / 8;  // rows per gather-team == rows per thread

  // ---- gather phase ----
  {
    const int team = tid >> 5;      // 0..7
    const int l4 = (tid & 31) * 4;  // float4 slot within row
#pragma unroll
    for (int rr = 0; rr < RPT; ++rr) {
      const int r = team * RPT + rr;
      int rg = rowBase + r;
      if (rg >= M) rg = M - 1;  // clamped read; stores guarded below
      const int deg = cnt[rg];
      const int nb = (deg < CAP) ? deg : CAP;
      const int* bk = bucket + (size_t)rg * CAP;
      float4 a0 = {0.f, 0.f, 0.f, 0.f}, a1 = a0, a2 = a0, a3 = a0;
      int e = 0;
      for (; e + 7 < nb; e += 8) {
        int s0 = bk[e], s1 = bk[e + 1], s2 = bk[e + 2], s3 = bk[e + 3];
        int s4 = bk[e + 4], s5 = bk[e + 5], s6 = bk[e + 6], s7 = bk[e + 7];
        float4 v0 = ld4(xsrc + (size_t)s0 * DD + l4);
        float4 v1 = ld4(xsrc + (size_t)s1 * DD + l4);
        float4 v2 = ld4(xsrc + (size_t)s2 * DD + l4);
        float4 v3 = ld4(xsrc + (size_t)s3 * DD + l4);
        float4 v4 = ld4(xsrc + (size_t)s4 * DD + l4);
        float4 v5 = ld4(xsrc + (size_t)s5 * DD + l4);
        float4 v6 = ld4(xsrc + (size_t)s6 * DD + l4);
        float4 v7 = ld4(xsrc + (size_t)s7 * DD + l4);
        a0.x += v0.x; a0.y += v0.y; a0.z += v0.z; a0.w += v0.w;
        a1.x += v1.x; a1.y += v1.y; a1.z += v1.z; a1.w += v1.w;
        a2.x += v2.x; a2.y += v2.y; a2.z += v2.z; a2.w += v2.w;
        a3.x += v3.x; a3.y += v3.y; a3.z += v3.z; a3.w += v3.w;
        a0.x += v4.x; a0.y += v4.y; a0.z += v4.z; a0.w += v4.w;
        a1.x += v5.x; a1.y += v5.y; a1.z += v5.z; a1.w += v5.w;
        a2.x += v6.x; a2.y += v6.y; a2.z += v6.z; a2.w += v6.w;
        a3.x += v7.x; a3.y += v7.y; a3.z += v7.z; a3.w += v7.w;
      }
      for (; e + 3 < nb; e += 4) {
        int s0 = bk[e], s1 = bk[e + 1], s2 = bk[e + 2], s3 = bk[e + 3];
        float4 v0 = ld4(xsrc + (size_t)s0 * DD + l4);
        float4 v1 = ld4(xsrc + (size_t)s1 * DD + l4);
        float4 v2 = ld4(xsrc + (size_t)s2 * DD + l4);
        float4 v3 = ld4(xsrc + (size_t)s3 * DD + l4);
        a0.x += v0.x; a0.y += v0.y; a0.z += v0.z; a0.w += v0.w;
        a1.x += v1.x; a1.y += v1.y; a1.z += v1.z; a1.w += v1.w;
        a2.x += v2.x; a2.y += v2.y; a2.z += v2.z; a2.w += v2.w;
        a3.x += v3.x; a3.y += v3.y; a3.z += v3.z; a3.w += v3.w;
      }
      for (; e < nb; ++e) {
        float4 v = ld4(xsrc + (size_t)bk[e] * DD + l4);
        a0.x += v.x; a0.y += v.y; a0.z += v.z; a0.w += v.w;
      }
      if (deg > CAP) {  // rare: scan compact overflow list for this row
        int ovc = *ovCnt;
        if (ovc > OVCAP) ovc = OVCAP;
        for (int o = 0; o < ovc; ++o) {
          if (ovList[2 * o] == rg) {
            float4 v = ld4(xsrc + (size_t)ovList[2 * o + 1] * DD + l4);
            a0.x += v.x; a0.y += v.y; a0.z += v.z; a0.w += v.w;
          }
        }
      }
      a0.x += a1.x + a2.x + a3.x;
      a0.y += a1.y + a2.y + a3.y;
      a0.z += a1.z + a2.z + a3.z;
      a0.w += a1.w + a2.w + a3.w;
      float rdeg = 1.0f / fmaxf((float)deg, 1.0f);
      a0.x *= rdeg; a0.y *= rdeg; a0.z *= rdeg; a0.w *= rdeg;
      *(float4*)(As + r * 256 + l4) = a0;
      *(float4*)(As + r * 256 + DD + l4) = ld4(xin + (size_t)rg * DD + l4);
    }
  }
  __syncthreads();

  // ---- dense phase: RPT rows x 4 cols per thread ----
  const int u = tid & 31;   // cols u, u+32, u+64, u+96
  const int g = tid >> 5;   // row group 0..7 (wave-uniform)
  const int r0 = g * RPT;
  float acc[RPT][4];
#pragma unroll
  for (int r = 0; r < RPT; ++r)
    acc[r][0] = acc[r][1] = acc[r][2] = acc[r][3] = 0.f;

#pragma unroll 8
  for (int k0 = 0; k0 < 256; k0 += 4) {
    const float* wbase = WTp + (k0 >> 2) * (DD * 4);
    float4 w0 = ld4(wbase + u * 4);
    float4 w1 = ld4(wbase + (u + 32) * 4);
    float4 w2 = ld4(wbase + (u + 64) * 4);
    float4 w3 = ld4(wbase + (u + 96) * 4);
#pragma unroll
    for (int r = 0; r < RPT; ++r) {
      float4 a = *(const float4*)(As + (r0 + r) * 256 + k0);
      acc[r][0] += a.x * w0.x + a.y * w0.y + a.z * w0.z + a.w * w0.w;
      acc[r][1] += a.x * w1.x + a.y * w1.y + a.z * w1.z + a.w * w1.w;
      acc[r][2] += a.x * w2.x + a.y * w2.y + a.z * w2.z + a.w * w2.w;
      acc[r][3] += a.x * w3.x + a.y * w3.y + a.z * w3.z + a.w * w3.w;
    }
  }

  float bb[4] = {bias[u], bias[u + 32], bias[u + 64], bias[u + 96]};
#pragma unroll
  for (int r = 0; r < RPT; ++r) {
    int rg = rowBase + r0 + r;
    if (rg >= M) continue;
#pragma unroll
    for (int i = 0; i < 4; ++i) {
      int cc = u + 32 * i;
      float v = acc[r][i] + bb[i];
      if (LAYER == 1) {
        v = fmaxf(v, 0.0f);
        v = dropout_keep((uint32_t)rg * DD + (uint32_t)cc) ? v * 2.0f : 0.0f;
      }
      out[(size_t)rg * DD + cc] = v;
    }
  }
}

extern "C" void kernel_launch(void* const* d_in, const int* in_sizes, int n_in,
                              void* d_out, int out_size, void* d_ws, size_t ws_size,
                              hipStream_t stream) {
  const float* feat = (const float*)d_in[0];   // fp32 (R4 NaN proof)
  const int* t_adj = (const int*)d_in[1];
  const int* n_adj = (const int*)d_in[2];
  const float* W1l = (const float*)d_in[5];
  const float* b1 = (const float*)d_in[6];
  const float* W1r = (const float*)d_in[7];
  const float* W2l = (const float*)d_in[8];
  const float* b2 = (const float*)d_in[9];
  const float* W2r = (const float*)d_in[10];

  const int E1 = in_sizes[1] / 2;
  const int E2 = in_sizes[2] / 2;

  // Workspace layout (ints unless noted). CAP sized from ws_size.
  float* ws = (float*)d_ws;
  float* x1 = ws;                          // 3,200,000 f
  float* WT1 = x1 + 3200000;               //    32,768 f
  float* WT2 = WT1 + 32768;                //    32,768 f
  int* cnt1 = (int*)(WT2 + 32768);         //    NJ
  int* cnt2 = cnt1 + NJ;                   //    NI
  int* ovCnt = cnt2 + NI;                  //    8 (2 used)
  int* ovList1 = ovCnt + 8;                //    2*OVCAP
  int* ovList2 = ovList1 + 2 * OVCAP;      //    2*OVCAP
  int* bucket1 = ovList2 + 2 * OVCAP;      //    NJ*CAP

  const long fixedInts = 3200000L + 32768 + 32768 + NJ + NI + 8 + 4L * OVCAP;
  long capInts = (long)(ws_size / 4) - fixedInts;
  int CAP = (int)(capInts / (NJ + NI));
  if (CAP > 64) CAP = 64;
  if (CAP < 16) CAP = 16;  // ws proven >= 19.6 MB by earlier rounds => >= 41

  int* bucket2 = bucket1 + (size_t)NJ * CAP;  // NI*CAP

  // Zero cnt1, cnt2, ovCnt (contiguous): (NJ+NI+8) ints.
  hipMemsetAsync(cnt1, 0, (size_t)(NJ + NI + 8) * sizeof(int), stream);

  const int nTot = E1 + E2;
  setup_bucket<<<256 + (nTot + 255) / 256, 256, 0, stream>>>(
      W1l, W1r, WT1, W2l, W2r, WT2, t_adj, n_adj, cnt1, cnt2, ovCnt, ovList1,
      ovList2, bucket1, bucket2, E1, E2, CAP);

  dense_kernel<32, 1><<<(NJ + 31) / 32, 256, 0, stream>>>(
      feat, bucket1, cnt1, ovCnt + 0, ovList1, feat, WT1, b1, x1, NJ, CAP);
  dense_kernel<16, 2><<<(NI + 15) / 16, 256, 0, stream>>>(
      x1, bucket2, cnt2, ovCnt + 1, ovList2, x1, WT2, b2, (float*)d_out, NI,
      CAP);
}